// Round 14
// baseline (3769.468 us; speedup 1.0000x reference)
//
#include <hip/hip_runtime.h>
#include <hip/hip_bf16.h>
#include <math.h>

static constexpr int NLAT = 128, NLON = 256, MM = 128;
static constexpr int EMB = 256, OUTCH = 6, HID = 512, NLAYERS = 4;
static constexpr int YN = 32768;
static constexpr long RB = 4194304;

using bf16x8 = __attribute__((ext_vector_type(8))) __bf16;
using f32x4  = __attribute__((ext_vector_type(4))) float;

static constexpr int BM = 128, BN = 128, BK = 32;

// ---- pair helpers: u32 = lo<<16 | hi ----
__device__ __forceinline__ uint packf(float v)
{
    union { __bf16 b[2]; uint u; } cv;
    const __bf16 h = (__bf16)v;
    cv.b[0] = h;
    cv.b[1] = (__bf16)(v - (float)h);
    return cv.u;
}
__device__ __forceinline__ float unpackf(uint u)
{
    union { uint u; __bf16 b[2]; } cv; cv.u = u;
    return (float)cv.b[0] + (float)cv.b[1];
}
__device__ __forceinline__ void unpack4(uint4 u, uint2& hi, uint2& lo)
{
    hi.x = (u.x & 0xffffu) | (u.y << 16);
    hi.y = (u.z & 0xffffu) | (u.w << 16);
    lo.x = (u.x >> 16) | (u.y & 0xffff0000u);
    lo.y = (u.z >> 16) | (u.w & 0xffff0000u);
}
__device__ __forceinline__ int swz(int r) { return (r & 3) ^ ((r >> 2) & 3); }

// XCD-bijective block remap (m204)
__device__ __forceinline__ void xcd_remap(uint& bx, uint& by, uint& bz)
{
    const uint gx = gridDim.x, gy = gridDim.y;
    const uint nwg = gx * gy * gridDim.z;
    const uint lin = (blockIdx.z * gy + blockIdx.y) * gx + blockIdx.x;
    const uint q = nwg >> 3, r = nwg & 7, xcd = lin & 7, o8 = lin >> 3;
    const uint logical = (xcd < r ? xcd * (q + 1) : r * (q + 1) + (xcd - r) * q) + o8;
    bz = logical / (gx * gy);
    const uint rem = logical % (gx * gy);
    by = rem / gx; bx = rem % gx;
}

// ============== split-bf16 NT GEMM, u32-pair operands ==============
__global__ __launch_bounds__(256)
void gemm_p(const uint* __restrict__ Ag, const uint* __restrict__ Bg,
            int M, int N, int K, int lda, int ldb, int ldc,
            long sAz, long sBz, unsigned zmaskB, long sCz,
            float* __restrict__ Cf, uint* __restrict__ Cp,
            const float* __restrict__ addf, const uint* __restrict__ addp,
            const float* __restrict__ bias, int kfromz, float alpha, int relu)
{
    __shared__ __bf16 lds[16384];   // Ah(0) Al(8KB) Bh(16KB) Bl(24KB) bytes

    uint bx, by, bz; xcd_remap(bx, by, bz);
    const int z = bz, m0 = by * BM, n0 = bx * BN;
    const long aOff = (long)z * sAz, bOff = (long)(z & zmaskB) * sBz, cOff = (long)z * sCz;
    const int kst = kfromz ? (((z & 127) >> 5) << 5) : 0;

    const int tid = threadIdx.x, lane = tid & 63, wave = tid >> 6;
    const int wr = wave >> 1, wc = wave & 1, fr = lane & 15, fkb = lane >> 4;
    const int strow = tid >> 1, stq = (tid & 1) * 4;
    const int ga = m0 + strow, gb = n0 + strow;
    const uint* Ar = Ag + aOff + (long)ga * lda;
    const uint* Br = Bg + bOff + (long)gb * ldb;
    const int sr = swz(strow);

    f32x4 acc[4][4];
    #pragma unroll
    for (int i = 0; i < 4; ++i)
        #pragma unroll
        for (int j = 0; j < 4; ++j) acc[i][j] = (f32x4)0.f;

    uint4 pa[4], pb[4];
    const uint4 z4 = make_uint4(0u, 0u, 0u, 0u);
    auto load = [&](int k0) {
        #pragma unroll
        for (int i = 0; i < 4; ++i) {
            const int kc = k0 + (stq + i) * 4;
            pa[i] = (ga < M) ? *(const uint4*)(Ar + kc) : z4;
            pb[i] = (gb < N) ? *(const uint4*)(Br + kc) : z4;
        }
    };
    auto commit = [&]() {
        #pragma unroll
        for (int i = 0; i < 4; ++i) {
            const int q = stq + i;
            const int boff = strow * 64 + (((q >> 1) ^ sr) << 4) + ((q & 1) << 3);
            uint2 hi, lo;
            unpack4(pa[i], hi, lo);
            *(uint2*)((char*)lds + boff) = hi;
            *(uint2*)((char*)lds + 8192 + boff) = lo;
            unpack4(pb[i], hi, lo);
            *(uint2*)((char*)lds + 16384 + boff) = hi;
            *(uint2*)((char*)lds + 24576 + boff) = lo;
        }
    };

    load(kst);
    for (int k0 = kst; k0 < K; k0 += BK) {
        commit();
        __syncthreads();
        if (k0 + BK < K) load(k0 + BK);

        bf16x8 fah[4], fal[4], fbh[4], fbl[4];
        #pragma unroll
        for (int i = 0; i < 4; ++i) {
            const int r = wr * 64 + i * 16 + fr;
            const int cb = r * 64 + ((fkb ^ swz(r)) << 4);
            fah[i] = *(const bf16x8*)((const char*)lds + cb);
            fal[i] = *(const bf16x8*)((const char*)lds + 8192 + cb);
        }
        #pragma unroll
        for (int j = 0; j < 4; ++j) {
            const int c = wc * 64 + j * 16 + fr;
            const int cb = c * 64 + ((fkb ^ swz(c)) << 4);
            fbh[j] = *(const bf16x8*)((const char*)lds + 16384 + cb);
            fbl[j] = *(const bf16x8*)((const char*)lds + 24576 + cb);
        }
        #pragma unroll
        for (int i = 0; i < 4; ++i)
            #pragma unroll
            for (int j = 0; j < 4; ++j) {
                acc[i][j] = __builtin_amdgcn_mfma_f32_16x16x32_bf16(fah[i], fbh[j], acc[i][j], 0, 0, 0);
                acc[i][j] = __builtin_amdgcn_mfma_f32_16x16x32_bf16(fah[i], fbl[j], acc[i][j], 0, 0, 0);
                acc[i][j] = __builtin_amdgcn_mfma_f32_16x16x32_bf16(fal[i], fbh[j], acc[i][j], 0, 0, 0);
            }
        __syncthreads();
    }

    const int crow0 = (lane >> 4) * 4;
    #pragma unroll
    for (int i = 0; i < 4; ++i)
        #pragma unroll
        for (int j = 0; j < 4; ++j)
            #pragma unroll
            for (int r = 0; r < 4; ++r) {
                const int gm = m0 + wr * 64 + i * 16 + crow0 + r;
                const int gn = n0 + wc * 64 + j * 16 + fr;
                if (gm < M && gn < N) {
                    const long idx = cOff + (long)gm * ldc + gn;
                    float v = acc[i][j][r] * alpha;
                    if (addf) v += addf[idx];
                    if (addp) v += unpackf(addp[idx]);
                    if (bias) v += bias[gn];
                    if (relu) v = fmaxf(v, 0.f);
                    if (Cf) Cf[idx] = v;
                    if (Cp) Cp[idx] = packf(v);
                }
            }
}

// ============== dual-output spec GEMM: C1=a1*W·B1 (+C1), C2=a2*W·B2 (+C2) ==============
__global__ __launch_bounds__(256)
void gemm_c(const uint* __restrict__ Wg, const uint* __restrict__ B1g, const uint* __restrict__ B2g,
            uint* __restrict__ C1, uint* __restrict__ C2,
            int M, int N, int K, int lda, int ldb, int ldc,
            long sAz, long sBz, long sCz,
            float a1, int acc1f, float a2, int acc2f)
{
    __shared__ __bf16 lds[24576];   // Wh Wl B1h B1l B2h B2l, 8KB each

    uint bx, by, bz; xcd_remap(bx, by, bz);
    const int z = bz, m0 = by * BM, n0 = bx * BN;
    const long aOff = (long)z * sAz, bOff = (long)z * sBz, cOff = (long)z * sCz;

    const int tid = threadIdx.x, lane = tid & 63, wave = tid >> 6;
    const int wr = wave >> 1, wc = wave & 1, fr = lane & 15, fkb = lane >> 4;
    const int strow = tid >> 1, stq = (tid & 1) * 4;
    const int ga = m0 + strow, gb = n0 + strow;
    const uint* Wr = Wg + aOff + (long)ga * lda;
    const uint* B1r = B1g + bOff + (long)gb * ldb;
    const uint* B2r = B2g + bOff + (long)gb * ldb;
    const int sr = swz(strow);

    f32x4 ac1[4][4], ac2[4][4];
    #pragma unroll
    for (int i = 0; i < 4; ++i)
        #pragma unroll
        for (int j = 0; j < 4; ++j) { ac1[i][j] = (f32x4)0.f; ac2[i][j] = (f32x4)0.f; }

    uint4 pw[4], p1[4], p2[4];
    const uint4 z4 = make_uint4(0u, 0u, 0u, 0u);
    auto load = [&](int k0) {
        #pragma unroll
        for (int i = 0; i < 4; ++i) {
            const int kc = k0 + (stq + i) * 4;
            pw[i] = (ga < M) ? *(const uint4*)(Wr + kc) : z4;
            p1[i] = (gb < N) ? *(const uint4*)(B1r + kc) : z4;
            p2[i] = (gb < N) ? *(const uint4*)(B2r + kc) : z4;
        }
    };
    auto commit = [&]() {
        #pragma unroll
        for (int i = 0; i < 4; ++i) {
            const int q = stq + i;
            const int boff = strow * 64 + (((q >> 1) ^ sr) << 4) + ((q & 1) << 3);
            uint2 hi, lo;
            unpack4(pw[i], hi, lo);
            *(uint2*)((char*)lds + boff) = hi;
            *(uint2*)((char*)lds + 8192 + boff) = lo;
            unpack4(p1[i], hi, lo);
            *(uint2*)((char*)lds + 16384 + boff) = hi;
            *(uint2*)((char*)lds + 24576 + boff) = lo;
            unpack4(p2[i], hi, lo);
            *(uint2*)((char*)lds + 32768 + boff) = hi;
            *(uint2*)((char*)lds + 40960 + boff) = lo;
        }
    };

    load(0);
    for (int k0 = 0; k0 < K; k0 += BK) {
        commit();
        __syncthreads();
        if (k0 + BK < K) load(k0 + BK);

        #pragma unroll
        for (int i = 0; i < 4; ++i) {
            const int r = wr * 64 + i * 16 + fr;
            const int cb = r * 64 + ((fkb ^ swz(r)) << 4);
            const bf16x8 wh = *(const bf16x8*)((const char*)lds + cb);
            const bf16x8 wl = *(const bf16x8*)((const char*)lds + 8192 + cb);
            #pragma unroll
            for (int j = 0; j < 4; ++j) {
                const int c = wc * 64 + j * 16 + fr;
                const int cb2 = c * 64 + ((fkb ^ swz(c)) << 4);
                const bf16x8 b1h = *(const bf16x8*)((const char*)lds + 16384 + cb2);
                const bf16x8 b1l = *(const bf16x8*)((const char*)lds + 24576 + cb2);
                const bf16x8 b2h = *(const bf16x8*)((const char*)lds + 32768 + cb2);
                const bf16x8 b2l = *(const bf16x8*)((const char*)lds + 40960 + cb2);
                ac1[i][j] = __builtin_amdgcn_mfma_f32_16x16x32_bf16(wh, b1h, ac1[i][j], 0, 0, 0);
                ac1[i][j] = __builtin_amdgcn_mfma_f32_16x16x32_bf16(wh, b1l, ac1[i][j], 0, 0, 0);
                ac1[i][j] = __builtin_amdgcn_mfma_f32_16x16x32_bf16(wl, b1h, ac1[i][j], 0, 0, 0);
                ac2[i][j] = __builtin_amdgcn_mfma_f32_16x16x32_bf16(wh, b2h, ac2[i][j], 0, 0, 0);
                ac2[i][j] = __builtin_amdgcn_mfma_f32_16x16x32_bf16(wh, b2l, ac2[i][j], 0, 0, 0);
                ac2[i][j] = __builtin_amdgcn_mfma_f32_16x16x32_bf16(wl, b2h, ac2[i][j], 0, 0, 0);
            }
        }
        __syncthreads();
    }

    const int crow0 = (lane >> 4) * 4;
    #pragma unroll
    for (int i = 0; i < 4; ++i)
        #pragma unroll
        for (int j = 0; j < 4; ++j)
            #pragma unroll
            for (int r = 0; r < 4; ++r) {
                const int gm = m0 + wr * 64 + i * 16 + crow0 + r;
                const int gn = n0 + wc * 64 + j * 16 + fr;
                if (gm < M && gn < N) {
                    const long idx = cOff + (long)gm * ldc + gn;
                    float v1 = ac1[i][j][r] * a1;
                    if (acc1f) v1 += unpackf(C1[idx]);
                    C1[idx] = packf(v1);
                    float v2 = ac2[i][j][r] * a2;
                    if (acc2f) v2 += unpackf(C2[idx]);
                    C2[idx] = packf(v2);
                }
            }
}

// ============== transposes (u32) ==============
__global__ __launch_bounds__(256)
void t2u(const uint* __restrict__ in, uint* __restrict__ out,
         int R, int C, long siZ, long soZ)
{
    __shared__ uint t[32][33];
    const int z = blockIdx.z;
    const long iB = (long)z * siZ, oB = (long)z * soZ;
    const int c0 = blockIdx.x * 32, r0 = blockIdx.y * 32;
    const int tx = threadIdx.x & 31, tg = threadIdx.x >> 5;
    #pragma unroll
    for (int rr = tg; rr < 32; rr += 8) {
        const int r = r0 + rr, c = c0 + tx;
        t[rr][tx] = (r < R && c < C) ? in[iB + (long)r * C + c] : 0u;
    }
    __syncthreads();
    #pragma unroll
    for (int cc = tg; cc < 32; cc += 8) {
        const int c = c0 + cc, r = r0 + tx;
        if (c < C && r < R) out[oB + (long)c * R + r] = t[tx][cc];
    }
}

__global__ __launch_bounds__(256)
void rot3u(const uint* __restrict__ in, uint* __restrict__ out,
           int Ad, int Bd, int Cd, long sIn, long sOut)
{
    __shared__ uint t[32][33];
    const int zz = blockIdx.z;
    const int b = zz % Bd, bat = zz / Bd;
    const long iB = (long)bat * sIn, oB = (long)bat * sOut;
    const int c0 = blockIdx.x * 32, a0 = blockIdx.y * 32;
    const int tx = threadIdx.x & 31, tg = threadIdx.x >> 5;
    #pragma unroll
    for (int aa = tg; aa < 32; aa += 8) {
        const int a = a0 + aa, c = c0 + tx;
        t[aa][tx] = (a < Ad && c < Cd) ? in[iB + ((long)a * Bd + b) * Cd + c] : 0u;
    }
    __syncthreads();
    #pragma unroll
    for (int cc = tg; cc < 32; cc += 8) {
        const int c = c0 + cc, a = a0 + tx;
        if (c < Cd && a < Ad) out[oB + ((long)c * Bd + b) * Ad + a] = t[tx][cc];
    }
}

// f32 [R][C] -> transposed u32-pair [C][Rd]
__global__ __launch_bounds__(256)
void t2cvtp(const float* __restrict__ in, uint* __restrict__ out, int R, int C, int Rd)
{
    __shared__ float t[32][33];
    const int c0 = blockIdx.x * 32, r0 = blockIdx.y * 32;
    const int tx = threadIdx.x & 31, tg = threadIdx.x >> 5;
    #pragma unroll
    for (int rr = tg; rr < 32; rr += 8) {
        const int r = r0 + rr, c = c0 + tx;
        t[rr][tx] = (r < R && c < C) ? in[(long)r * C + c] : 0.f;
    }
    __syncthreads();
    #pragma unroll
    for (int cc = tg; cc < 32; cc += 8) {
        const int c = c0 + cc, r = r0 + tx;
        if (c < C && r < Rd) out[(long)c * Rd + r] = packf(t[tx][cc]);
    }
}

__global__ __launch_bounds__(256)
void transpose2d(const float* __restrict__ in, float* __restrict__ out, int R, int C)
{
    __shared__ float t[32][33];
    const int c0 = blockIdx.x * 32, r0 = blockIdx.y * 32;
    const int tx = threadIdx.x & 31, tg = threadIdx.x >> 5;
    #pragma unroll
    for (int rr = tg; rr < 32; rr += 8) {
        const int r = r0 + rr, c = c0 + tx;
        t[rr][tx] = (r < R && c < C) ? in[(long)r * C + c] : 0.f;
    }
    __syncthreads();
    #pragma unroll
    for (int cc = tg; cc < 32; cc += 8) {
        const int c = c0 + cc, r = r0 + tx;
        if (c < C && r < R) out[(long)c * R + r] = t[tx][cc];
    }
}

// f32 [Rsrc][Ks] (stride sld) -> u32-pair [Rdst][Kd]
__global__ __launch_bounds__(256)
void cvtp(const float* __restrict__ src, uint* __restrict__ out,
          int Rsrc, int Rdst, int Ks, int Kd, int sld)
{
    const long i = (long)blockIdx.x * 256 + threadIdx.x;
    if (i >= (long)Rdst * Kd) return;
    const int r = (int)(i / Kd), k = (int)(i % Kd);
    out[i] = packf((r < Rsrc && k < Ks) ? src[(long)r * sld + k] : 0.f);
}

// ============== table builders ==============
__global__ __launch_bounds__(256)
void make_dft_u(uint* Wf, uint* Wi2)
{
    const int i = blockIdx.x * 256 + threadIdx.x;
    const double w0 = 2.0 * 3.14159265358979323846 / 256.0;
    {
        const int n = i & 255, r = i >> 8, m = r & 127;
        const double th = (double)((m * n) & 255) * w0;
        Wf[i] = packf((r < 128) ? (float)cos(th) : (float)-sin(th));
    }
    {
        const int k = i & 255, nn = i >> 8, m = k & 127;
        const double th = (double)((m * nn) & 255) * w0;
        const float sc = (m == 0 ? 1.0f : 2.0f) / 256.0f;
        Wi2[i] = packf((k < 128) ? sc * (float)cos(th) : -sc * (float)sin(th));
    }
}

__global__ __launch_bounds__(256)
void make_P1_u(const float* __restrict__ pct, const float* __restrict__ wq, uint* __restrict__ P1)
{
    const long i = (long)blockIdx.x * 256 + threadIdx.x;
    const int y = (int)(i & 127);
    const int l = (int)((i >> 7) & 127);
    const int m = (int)(i >> 14);
    P1[i] = packf(pct[((long)l * MM + m) * NLAT + y] * wq[y]);
}

__global__ __launch_bounds__(256)
void make_Q_u(const float* __restrict__ pct, uint* __restrict__ Q)
{
    __shared__ float t[32][33];
    const int m = blockIdx.z;
    const int y0 = blockIdx.x * 32, l0 = blockIdx.y * 32;
    const int tx = threadIdx.x & 31, tg = threadIdx.x >> 5;
    #pragma unroll
    for (int ll = tg; ll < 32; ll += 8)
        t[ll][tx] = pct[((long)(l0 + ll) * MM + m) * NLAT + (y0 + tx)];
    __syncthreads();
    #pragma unroll
    for (int yy = tg; yy < 32; yy += 8)
        Q[((long)m * NLAT + (y0 + yy)) * MM + (l0 + tx)] = packf(t[tx][yy]);
}

// ============== host ==============
extern "C" void kernel_launch(void* const* d_in, const int* in_sizes, int n_in,
                              void* d_out, int out_size, void* d_ws, size_t ws_size,
                              hipStream_t stream)
{
    const float* x       = (const float*)d_in[0];
    const float* pct     = (const float*)d_in[1];
    const float* wq      = (const float*)d_in[2];
    const float* pos     = (const float*)d_in[3];
    const float* enc_w   = (const float*)d_in[4];
    const float* spec_re = (const float*)d_in[5];
    const float* spec_im = (const float*)d_in[6];
    const float* skip_w  = (const float*)d_in[7];
    const float* skip_b  = (const float*)d_in[8];
    const float* mlp_w1  = (const float*)d_in[9];
    const float* mlp_b1  = (const float*)d_in[10];
    const float* mlp_w2  = (const float*)d_in[11];
    const float* mlp_b2  = (const float*)d_in[12];
    const float* dec_w1  = (const float*)d_in[13];
    const float* dec_b1  = (const float*)d_in[14];
    const float* dec_w2  = (const float*)d_in[15];

    char* base = (char*)d_ws;
    size_t off = 0;
    auto alloc = [&](size_t bytes) -> char* {
        char* p = base + off; off += (bytes + 255) & ~(size_t)255; return p;
    };
    auto allocU = [&](long elems) -> uint* { return (uint*)alloc((size_t)elems * 4); };

    uint* Wf  = allocU(65536);
    uint* Wi2 = allocU(65536);
    uint* P1  = allocU(2097152);
    uint* Q   = allocU(2097152);
    uint* enc = allocU(256 * 64);
    uint* skp = allocU(4L * 65536);
    uint* w1  = allocU(4L * 131072);
    uint* w2  = allocU(4L * 131072);
    uint* d1h = allocU(512 * 256);
    uint* d1x = allocU(512 * 64);
    uint* d2  = allocU(128 * 512);
    uint* xT  = allocU((long)YN * 64);
    float* posT = (float*)alloc((size_t)8388608 * 4);
    uint* hA  = allocU(8388608);
    uint* hB  = allocU(8388608);
    uint* S1  = allocU(8388608);
    uint* S2  = allocU(8388608);
    uint* mb  = allocU(16777216);
    uint* WtR = allocU(8388608);
    uint* WtI = allocU(8388608);
    float* U = (float*)alloc((size_t)8388608 * 4);
    float* D = (float*)alloc((size_t)16777216 * 4);
    if (off > ws_size) return;

    make_dft_u<<<256, 256, 0, stream>>>(Wf, Wi2);
    make_P1_u<<<8192, 256, 0, stream>>>(pct, wq, P1);
    make_Q_u<<<dim3(4, 4, 128), 256, 0, stream>>>(pct, Q);
    cvtp<<<(256 * 64 + 255) / 256, 256, 0, stream>>>(enc_w, enc, 256, 256, 36, 64, 36);
    cvtp<<<(1024 * 256 + 255) / 256, 256, 0, stream>>>(skip_w, skp, 1024, 1024, 256, 256, 256);
    cvtp<<<(2048 * 256 + 255) / 256, 256, 0, stream>>>(mlp_w1, w1, 2048, 2048, 256, 256, 256);
    cvtp<<<(1024 * 512 + 255) / 256, 256, 0, stream>>>(mlp_w2, w2, 1024, 1024, 512, 512, 512);
    cvtp<<<(512 * 256 + 255) / 256, 256, 0, stream>>>(dec_w1, d1h, 512, 512, 256, 256, 292);
    cvtp<<<(512 * 64 + 255) / 256, 256, 0, stream>>>(dec_w1 + 256, d1x, 512, 512, 36, 64, 292);
    cvtp<<<(128 * 512 + 255) / 256, 256, 0, stream>>>(dec_w2, d2, 6, 128, 512, 512, 512);
    t2cvtp<<<dim3(1024, 2), 256, 0, stream>>>(x, xT, 36, YN, 64);
    transpose2d<<<dim3(1024, 8), 256, 0, stream>>>(pos, posT, 256, YN);

    auto g = [&](const uint* A, const uint* B, int M, int N, int K,
                 int lda, int ldb, int ldc, long sAz, long sBz, unsigned zm, long sCz, int Z,
                 float* Cf, uint* Cp, const float* addf, const uint* addp,
                 const float* bias, int kfz, float alpha, int relu) {
        dim3 grid((N + BN - 1) / BN, (M + BM - 1) / BM, Z);
        gemm_p<<<grid, 256, 0, stream>>>(A, B, M, N, K, lda, ldb, ldc, sAz, sBz, zm, sCz,
                                         Cf, Cp, addf, addp, bias, kfz, alpha, relu);
    };

    // encoder
    g(xT, enc, YN, EMB, 64, 64, 64, EMB, 0, 0, 0u, 0, 1,
      nullptr, hA, posT, nullptr, nullptr, 0, 1.0f, 0);

    uint* hcur = hA;
    uint* hnext = hB;

    for (int l = 0; l < NLAYERS; ++l) {
        t2u<<<dim3(8, 1024, 1), 256, 0, stream>>>(hcur, S1, YN, 256, 0, 0);
        g(Wf, S1, 256, YN, 256, 256, 256, YN, 0, 0, 0u, 0, 1,
          nullptr, S2, nullptr, nullptr, nullptr, 0, 1.0f, 0);
        g(S2, P1, 256, 128, 128, 128, 128, 128, 32768, 16384, 127u, 32768, 256,
          nullptr, S1, nullptr, nullptr, nullptr, 0, 1.0f, 0);
        t2u<<<dim3(4, 1024, 2), 256, 0, stream>>>(S1, S2, 32768, 128, RB, RB);
        t2cvtp<<<dim3(4, 2048), 256, 0, stream>>>(spec_re + (long)l * 8388608, WtR, 65536, 128, 65536);
        t2cvtp<<<dim3(4, 2048), 256, 0, stream>>>(spec_im + (long)l * 8388608, WtI, 65536, 128, 65536);
        // Bre = Wr·Ar ; Bim = Wr·Ai
        gemm_c<<<dim3(1, 2, 128), 256, 0, stream>>>(WtR, S2, S2 + RB, S1, S1 + RB,
            256, 128, 256, 256, 256, 128, 65536, 32768, 32768, 1.0f, 0, 1.0f, 0);
        // Bre -= Wi·Ai ; Bim += Wi·Ar
        gemm_c<<<dim3(1, 2, 128), 256, 0, stream>>>(WtI, S2 + RB, S2, S1, S1 + RB,
            256, 128, 256, 256, 256, 128, 65536, 32768, 32768, -1.0f, 1, 1.0f, 1);
        rot3u<<<dim3(4, 4, 512), 256, 0, stream>>>(S1, S2, 128, 256, 128, RB, RB);
        g(S2, Q, 256, 128, 128, 128, 128, 128, 32768, 16384, 127u, 32768, 256,
          nullptr, S1, nullptr, nullptr, nullptr, 1, 1.0f, 0);
        t2u<<<dim3(1024, 8, 1), 256, 0, stream>>>(S1, S2, 256, YN, 0, 0);
        g(Wi2, S2, 256, 256, 256, 256, 32768, 256, 0, 256, 0xFFFFFFFFu, 65536, 128,
          U, nullptr, nullptr, nullptr, nullptr, 0, 1.0f, 0);
        g(hcur, skp + (long)l * 65536, YN, EMB, 256, 256, 256, EMB, 0, 0, 0u, 0, 1,
          nullptr, S1, U, nullptr, skip_b + (long)l * EMB, 0, 1.0f, 0);
        g(S1, w1 + (long)l * 131072, YN, HID, 256, 256, 256, HID, 0, 0, 0u, 0, 1,
          nullptr, mb, nullptr, nullptr, mlp_b1 + (long)l * HID, 0, 1.0f, 1);
        g(mb, w2 + (long)l * 131072, YN, EMB, 512, 512, 512, EMB, 0, 0, 0u, 0, 1,
          nullptr, hnext, nullptr, hcur, mlp_b2 + (long)l * EMB, 0, 1.0f, 0);
        uint* t = hcur; hcur = hnext; hnext = t;
    }

    // decoder
    g(hcur, d1h, YN, HID, 256, 256, 256, HID, 0, 0, 0u, 0, 1,
      D, nullptr, nullptr, nullptr, nullptr, 0, 1.0f, 0);
    g(xT, d1x, YN, HID, 64, 64, 64, HID, 0, 0, 0u, 0, 1,
      nullptr, mb, D, nullptr, dec_b1, 0, 1.0f, 1);
    g(mb, d2, YN, OUTCH, 512, 512, 512, OUTCH, 0, 0, 0u, 0, 1,
      U, nullptr, nullptr, nullptr, nullptr, 0, 1.0f, 0);
    transpose2d<<<dim3(1, 1024), 256, 0, stream>>>(U, (float*)d_out, YN, OUTCH);

    (void)in_sizes; (void)n_in; (void)out_size;
}

// Round 15
// 1780.397 us; speedup vs baseline: 2.1172x; 2.1172x over previous
//
#include <hip/hip_runtime.h>
#include <hip/hip_bf16.h>
#include <math.h>

static constexpr int NLAT = 128, NLON = 256, MM = 128;
static constexpr int EMB = 256, INCH = 36, OUTCH = 6, HID = 512, NLAYERS = 4;
static constexpr int YN = 32768;
static constexpr long RB = 4194304;   // per-reim block, elements

using bf16x8 = __attribute__((ext_vector_type(8))) __bf16;
using f32x4  = __attribute__((ext_vector_type(4))) float;

static constexpr int BM = 128, BN = 128, BK = 32, LDP = 40;

__device__ __forceinline__ void cvt_hl(float v, __bf16& h, __bf16& l)
{
    h = (__bf16)v;
    l = (__bf16)(v - (float)h);
}
__device__ __forceinline__ void pack_hi_lo(const float* v, bf16x8& h0, bf16x8& h1,
                                           bf16x8& l0, bf16x8& l1)
{
    #pragma unroll
    for (int e = 0; e < 8; ++e) {
        const __bf16 h = (__bf16)v[e];
        h0[e] = h; l0[e] = (__bf16)(v[e] - (float)h);
        const __bf16 g = (__bf16)v[e + 8];
        h1[e] = g; l1[e] = (__bf16)(v[e + 8] - (float)g);
    }
}

// ======================= f32-input split NT GEMM (round-11 proven) =======================
__global__ __launch_bounds__(256)
void gemm_nt(const float* __restrict__ A, const float* __restrict__ B,
             float* __restrict__ C, int M, int N, int K,
             int lda, int ldb, int ldc,
             const float* __restrict__ bias, int biasCol,
             const float* __restrict__ addsrc,
             float alpha, int accum, int relu)
{
    __shared__ __bf16 Ah[BM][LDP], Al[BM][LDP], Bh[BN][LDP], Bl[BN][LDP];

    const int m0 = blockIdx.y * BM, n0 = blockIdx.x * BN;
    const int tid = threadIdx.x, lane = tid & 63, wave = tid >> 6;
    const int wr = wave >> 1, wc = wave & 1;
    const int fr = lane & 15, fkb = lane >> 4;
    const int sr = tid >> 1, sh = (tid & 1) << 4;

    f32x4 acc[4][4];
    #pragma unroll
    for (int i = 0; i < 4; ++i)
        #pragma unroll
        for (int j = 0; j < 4; ++j) acc[i][j] = (f32x4)0.f;

    const int ga = m0 + sr, gb = n0 + sr;
    const float* Arow = A + (long)ga * lda + sh;
    const float* Brow = B + (long)gb * ldb + sh;

    bf16x8 sAh0, sAh1, sAl0, sAl1, sBh0, sBh1, sBl0, sBl1;

    auto loadA = [&](int k0) {
        float v[16];
        if (ga < M && (k0 + sh + 16) <= K) {
            #pragma unroll
            for (int q = 0; q < 4; ++q) {
                const float4 f = *(const float4*)(Arow + k0 + q * 4);
                v[q*4+0]=f.x; v[q*4+1]=f.y; v[q*4+2]=f.z; v[q*4+3]=f.w;
            }
        } else {
            #pragma unroll
            for (int e = 0; e < 16; ++e)
                v[e] = (ga < M && (k0 + sh + e) < K) ? Arow[k0 + e] : 0.f;
        }
        pack_hi_lo(v, sAh0, sAh1, sAl0, sAl1);
    };
    auto loadB = [&](int k0) {
        float v[16];
        if (gb < N && (k0 + sh + 16) <= K) {
            #pragma unroll
            for (int q = 0; q < 4; ++q) {
                const float4 f = *(const float4*)(Brow + k0 + q * 4);
                v[q*4+0]=f.x; v[q*4+1]=f.y; v[q*4+2]=f.z; v[q*4+3]=f.w;
            }
        } else {
            #pragma unroll
            for (int e = 0; e < 16; ++e)
                v[e] = (gb < N && (k0 + sh + e) < K) ? Brow[k0 + e] : 0.f;
        }
        pack_hi_lo(v, sBh0, sBh1, sBl0, sBl1);
    };

    loadA(0); loadB(0);

    for (int k0 = 0; k0 < K; k0 += BK) {
        *(bf16x8*)&Ah[sr][sh]     = sAh0;  *(bf16x8*)&Ah[sr][sh + 8] = sAh1;
        *(bf16x8*)&Al[sr][sh]     = sAl0;  *(bf16x8*)&Al[sr][sh + 8] = sAl1;
        *(bf16x8*)&Bh[sr][sh]     = sBh0;  *(bf16x8*)&Bh[sr][sh + 8] = sBh1;
        *(bf16x8*)&Bl[sr][sh]     = sBl0;  *(bf16x8*)&Bl[sr][sh + 8] = sBl1;
        __syncthreads();

        if (k0 + BK < K) { loadA(k0 + BK); loadB(k0 + BK); }

        bf16x8 fah[4], fal[4], fbh[4], fbl[4];
        #pragma unroll
        for (int i = 0; i < 4; ++i) {
            const int r = wr * 64 + i * 16 + fr;
            fah[i] = *(const bf16x8*)&Ah[r][fkb * 8];
            fal[i] = *(const bf16x8*)&Al[r][fkb * 8];
        }
        #pragma unroll
        for (int j = 0; j < 4; ++j) {
            const int c = wc * 64 + j * 16 + fr;
            fbh[j] = *(const bf16x8*)&Bh[c][fkb * 8];
            fbl[j] = *(const bf16x8*)&Bl[c][fkb * 8];
        }
        #pragma unroll
        for (int i = 0; i < 4; ++i)
            #pragma unroll
            for (int j = 0; j < 4; ++j) {
                acc[i][j] = __builtin_amdgcn_mfma_f32_16x16x32_bf16(fah[i], fbh[j], acc[i][j], 0, 0, 0);
                acc[i][j] = __builtin_amdgcn_mfma_f32_16x16x32_bf16(fah[i], fbl[j], acc[i][j], 0, 0, 0);
                acc[i][j] = __builtin_amdgcn_mfma_f32_16x16x32_bf16(fal[i], fbh[j], acc[i][j], 0, 0, 0);
            }
        __syncthreads();
    }

    const int crow0 = (lane >> 4) * 4;
    #pragma unroll
    for (int i = 0; i < 4; ++i)
        #pragma unroll
        for (int j = 0; j < 4; ++j)
            #pragma unroll
            for (int r = 0; r < 4; ++r) {
                const int gm = m0 + wr * 64 + i * 16 + crow0 + r;
                const int gn = n0 + wc * 64 + j * 16 + fr;
                if (gm < M && gn < N) {
                    const long idx = (long)gm * ldc + gn;
                    float v = acc[i][j][r] * alpha;
                    if (accum)  v += C[idx];
                    if (bias)   v += bias[biasCol ? gn : gm];
                    if (addsrc) v += addsrc[idx];
                    if (relu)   v = fmaxf(v, 0.f);
                    C[idx] = v;
                }
            }
}

// ======================= bf16 spectral NT GEMM =======================
// terms: A·B (+ Al·B if Al) (+ A·Bl if Bl). out: f32 and/or bf16.
__global__ __launch_bounds__(256)
void gemm_sp(const __bf16* __restrict__ Ah, const __bf16* __restrict__ Al,
             const __bf16* __restrict__ Bh, const __bf16* __restrict__ Bl,
             int M, int N, int K, int lda, int ldb, int ldc,
             long sAz, long sBz, unsigned zmaskB, long sCz,
             float* __restrict__ outF, __bf16* __restrict__ outB,
             float alpha, int kfromz)
{
    __shared__ __bf16 L0[BM * LDP], L1[BN * LDP], L2[BM * LDP];

    const int z = blockIdx.z;
    const long aOff = (long)z * sAz, bOff = (long)(z & zmaskB) * sBz, cOff = (long)z * sCz;
    const int m0 = blockIdx.y * BM, n0 = blockIdx.x * BN;
    const int tid = threadIdx.x, lane = tid & 63, wave = tid >> 6;
    const int wr = wave >> 1, wc = wave & 1, fr = lane & 15, fkb = lane >> 4;
    const int row = tid >> 1, half = (tid & 1) << 4;
    const int kst = kfromz ? (((z & 127) >> 5) << 5) : 0;
    const bool asp = (Al != nullptr), bsp = (Bl != nullptr);

    const __bf16* Ar = Ah + aOff + (long)(m0 + row) * lda + half;
    const __bf16* Br = Bh + bOff + (long)(n0 + row) * ldb + half;
    const __bf16* Xr = asp ? (Al + aOff + (long)(m0 + row) * lda + half)
                     : (bsp ? (Bl + bOff + (long)(n0 + row) * ldb + half) : nullptr);

    f32x4 acc[4][4];
    #pragma unroll
    for (int i = 0; i < 4; ++i)
        #pragma unroll
        for (int j = 0; j < 4; ++j) acc[i][j] = (f32x4)0.f;

    bf16x8 rA0, rA1, rB0, rB1, rX0, rX1;
    auto load = [&](int k0) {
        rA0 = *(const bf16x8*)(Ar + k0); rA1 = *(const bf16x8*)(Ar + k0 + 8);
        rB0 = *(const bf16x8*)(Br + k0); rB1 = *(const bf16x8*)(Br + k0 + 8);
        if (Xr) { rX0 = *(const bf16x8*)(Xr + k0); rX1 = *(const bf16x8*)(Xr + k0 + 8); }
    };
    load(kst);

    for (int k0 = kst; k0 < K; k0 += BK) {
        *(bf16x8*)&L0[row * LDP + half] = rA0; *(bf16x8*)&L0[row * LDP + half + 8] = rA1;
        *(bf16x8*)&L1[row * LDP + half] = rB0; *(bf16x8*)&L1[row * LDP + half + 8] = rB1;
        if (Xr) { *(bf16x8*)&L2[row * LDP + half] = rX0; *(bf16x8*)&L2[row * LDP + half + 8] = rX1; }
        __syncthreads();
        if (k0 + BK < K) load(k0 + BK);

        bf16x8 fa[4], fb[4], fx[4];
        #pragma unroll
        for (int i = 0; i < 4; ++i)
            fa[i] = *(const bf16x8*)&L0[(wr * 64 + i * 16 + fr) * LDP + fkb * 8];
        #pragma unroll
        for (int j = 0; j < 4; ++j)
            fb[j] = *(const bf16x8*)&L1[(wc * 64 + j * 16 + fr) * LDP + fkb * 8];
        if (asp) {
            #pragma unroll
            for (int i = 0; i < 4; ++i)
                fx[i] = *(const bf16x8*)&L2[(wr * 64 + i * 16 + fr) * LDP + fkb * 8];
        } else if (bsp) {
            #pragma unroll
            for (int j = 0; j < 4; ++j)
                fx[j] = *(const bf16x8*)&L2[(wc * 64 + j * 16 + fr) * LDP + fkb * 8];
        }
        #pragma unroll
        for (int i = 0; i < 4; ++i)
            #pragma unroll
            for (int j = 0; j < 4; ++j) {
                acc[i][j] = __builtin_amdgcn_mfma_f32_16x16x32_bf16(fa[i], fb[j], acc[i][j], 0, 0, 0);
                if (asp) acc[i][j] = __builtin_amdgcn_mfma_f32_16x16x32_bf16(fx[i], fb[j], acc[i][j], 0, 0, 0);
                else if (bsp) acc[i][j] = __builtin_amdgcn_mfma_f32_16x16x32_bf16(fa[i], fx[j], acc[i][j], 0, 0, 0);
            }
        __syncthreads();
    }

    const int crow0 = (lane >> 4) * 4;
    #pragma unroll
    for (int i = 0; i < 4; ++i)
        #pragma unroll
        for (int j = 0; j < 4; ++j)
            #pragma unroll
            for (int r = 0; r < 4; ++r) {
                const int gm = m0 + wr * 64 + i * 16 + crow0 + r;
                const int gn = n0 + wc * 64 + j * 16 + fr;
                const long idx = cOff + (long)gm * ldc + gn;
                const float v = acc[i][j][r] * alpha;
                if (outF) outF[idx] = v;
                if (outB) outB[idx] = (__bf16)v;
            }
}

// ======================= fused dual spec GEMM: C1 = a1*W·B1 (+C1), C2 = a2*W·B2 (+C2) ======
__global__ __launch_bounds__(256)
void gemm_c2(const __bf16* __restrict__ W, const __bf16* __restrict__ B1,
             const __bf16* __restrict__ B2,
             __bf16* __restrict__ C1, __bf16* __restrict__ C2,
             int K, int lda, int ldb, int ldc,
             long sAz, long sBz, long sCz,
             float a1, int acc1, float a2, int acc2)
{
    __shared__ __bf16 L0[BM * LDP], L1[BN * LDP], L2[BN * LDP];

    const int z = blockIdx.z;
    const long aOff = (long)z * sAz, bOff = (long)z * sBz, cOff = (long)z * sCz;
    const int m0 = blockIdx.y * BM, n0 = blockIdx.x * BN;
    const int tid = threadIdx.x, lane = tid & 63, wave = tid >> 6;
    const int wr = wave >> 1, wc = wave & 1, fr = lane & 15, fkb = lane >> 4;
    const int row = tid >> 1, half = (tid & 1) << 4;

    const __bf16* Ar  = W  + aOff + (long)(m0 + row) * lda + half;
    const __bf16* B1r = B1 + bOff + (long)(n0 + row) * ldb + half;
    const __bf16* B2r = B2 + bOff + (long)(n0 + row) * ldb + half;

    f32x4 ac1[4][4], ac2[4][4];
    #pragma unroll
    for (int i = 0; i < 4; ++i)
        #pragma unroll
        for (int j = 0; j < 4; ++j) { ac1[i][j] = (f32x4)0.f; ac2[i][j] = (f32x4)0.f; }

    bf16x8 rA0, rA1, r10, r11, r20, r21;
    auto load = [&](int k0) {
        rA0 = *(const bf16x8*)(Ar + k0);  rA1 = *(const bf16x8*)(Ar + k0 + 8);
        r10 = *(const bf16x8*)(B1r + k0); r11 = *(const bf16x8*)(B1r + k0 + 8);
        r20 = *(const bf16x8*)(B2r + k0); r21 = *(const bf16x8*)(B2r + k0 + 8);
    };
    load(0);

    for (int k0 = 0; k0 < K; k0 += BK) {
        *(bf16x8*)&L0[row * LDP + half] = rA0; *(bf16x8*)&L0[row * LDP + half + 8] = rA1;
        *(bf16x8*)&L1[row * LDP + half] = r10; *(bf16x8*)&L1[row * LDP + half + 8] = r11;
        *(bf16x8*)&L2[row * LDP + half] = r20; *(bf16x8*)&L2[row * LDP + half + 8] = r21;
        __syncthreads();
        if (k0 + BK < K) load(k0 + BK);

        bf16x8 fa[4], f1[4], f2[4];
        #pragma unroll
        for (int i = 0; i < 4; ++i)
            fa[i] = *(const bf16x8*)&L0[(wr * 64 + i * 16 + fr) * LDP + fkb * 8];
        #pragma unroll
        for (int j = 0; j < 4; ++j) {
            f1[j] = *(const bf16x8*)&L1[(wc * 64 + j * 16 + fr) * LDP + fkb * 8];
            f2[j] = *(const bf16x8*)&L2[(wc * 64 + j * 16 + fr) * LDP + fkb * 8];
        }
        #pragma unroll
        for (int i = 0; i < 4; ++i)
            #pragma unroll
            for (int j = 0; j < 4; ++j) {
                ac1[i][j] = __builtin_amdgcn_mfma_f32_16x16x32_bf16(fa[i], f1[j], ac1[i][j], 0, 0, 0);
                ac2[i][j] = __builtin_amdgcn_mfma_f32_16x16x32_bf16(fa[i], f2[j], ac2[i][j], 0, 0, 0);
            }
        __syncthreads();
    }

    const int crow0 = (lane >> 4) * 4;
    #pragma unroll
    for (int i = 0; i < 4; ++i)
        #pragma unroll
        for (int j = 0; j < 4; ++j)
            #pragma unroll
            for (int r = 0; r < 4; ++r) {
                const int gm = m0 + wr * 64 + i * 16 + crow0 + r;
                const int gn = n0 + wc * 64 + j * 16 + fr;
                const long idx = cOff + (long)gm * ldc + gn;
                float v1 = ac1[i][j][r] * a1;
                if (acc1) v1 += (float)C1[idx];
                C1[idx] = (__bf16)v1;
                float v2 = ac2[i][j][r] * a2;
                if (acc2) v2 += (float)C2[idx];
                C2[idx] = (__bf16)v2;
            }
}

// ======================= transposes =======================
__global__ __launch_bounds__(256)
void transpose2d(const float* __restrict__ in, float* __restrict__ out, int R, int C)
{
    __shared__ float t[32][33];
    const int c0 = blockIdx.x * 32, r0 = blockIdx.y * 32;
    const int tx = threadIdx.x & 31, tg = threadIdx.x >> 5;
    #pragma unroll
    for (int rr = tg; rr < 32; rr += 8) {
        const int r = r0 + rr, c = c0 + tx;
        t[rr][tx] = (r < R && c < C) ? in[(long)r * C + c] : 0.f;
    }
    __syncthreads();
    #pragma unroll
    for (int cc = tg; cc < 32; cc += 8) {
        const int c = c0 + cc, r = r0 + tx;
        if (c < C && r < R) out[(long)c * R + r] = t[tx][cc];
    }
}

// f32 [R][C] -> transposed bf16 [C][R]
__global__ __launch_bounds__(256)
void t_f2b(const float* __restrict__ in, __bf16* __restrict__ out, int R, int C)
{
    __shared__ float t[32][33];
    const int c0 = blockIdx.x * 32, r0 = blockIdx.y * 32;
    const int tx = threadIdx.x & 31, tg = threadIdx.x >> 5;
    #pragma unroll
    for (int rr = tg; rr < 32; rr += 8) {
        const int r = r0 + rr, c = c0 + tx;
        t[rr][tx] = (r < R && c < C) ? in[(long)r * C + c] : 0.f;
    }
    __syncthreads();
    #pragma unroll
    for (int cc = tg; cc < 32; cc += 8) {
        const int c = c0 + cc, r = r0 + tx;
        if (c < C && r < R) out[(long)c * R + r] = (__bf16)t[tx][cc];
    }
}

// bf16 transpose, batched: in[z][R][C] -> out[z][C][R]
__global__ __launch_bounds__(256)
void t_b(const __bf16* __restrict__ in, __bf16* __restrict__ out,
         int R, int C, long siZ, long soZ)
{
    __shared__ __bf16 t[32][34];
    const int z = blockIdx.z;
    const long iB = (long)z * siZ, oB = (long)z * soZ;
    const int c0 = blockIdx.x * 32, r0 = blockIdx.y * 32;
    const int tx = threadIdx.x & 31, tg = threadIdx.x >> 5;
    #pragma unroll
    for (int rr = tg; rr < 32; rr += 8) {
        const int r = r0 + rr, c = c0 + tx;
        t[rr][tx] = (r < R && c < C) ? in[iB + (long)r * C + c] : (__bf16)0.f;
    }
    __syncthreads();
    #pragma unroll
    for (int cc = tg; cc < 32; cc += 8) {
        const int c = c0 + cc, r = r0 + tx;
        if (c < C && r < R) out[oB + (long)c * R + r] = t[tx][cc];
    }
}

// bf16 rot: in[bat][a][b][c] -> out[bat][c][b][a]
__global__ __launch_bounds__(256)
void rot3b(const __bf16* __restrict__ in, __bf16* __restrict__ out,
           int Ad, int Bd, int Cd, long sIn, long sOut)
{
    __shared__ __bf16 t[32][34];
    const int zz = blockIdx.z;
    const int b = zz % Bd, bat = zz / Bd;
    const long iB = (long)bat * sIn, oB = (long)bat * sOut;
    const int c0 = blockIdx.x * 32, a0 = blockIdx.y * 32;
    const int tx = threadIdx.x & 31, tg = threadIdx.x >> 5;
    #pragma unroll
    for (int aa = tg; aa < 32; aa += 8) {
        const int a = a0 + aa, c = c0 + tx;
        t[aa][tx] = (a < Ad && c < Cd) ? in[iB + ((long)a * Bd + b) * Cd + c] : (__bf16)0.f;
    }
    __syncthreads();
    #pragma unroll
    for (int cc = tg; cc < 32; cc += 8) {
        const int c = c0 + cc, a = a0 + tx;
        if (c < Cd && a < Ad) out[oB + ((long)c * Bd + b) * Ad + a] = t[tx][cc];
    }
}

// ======================= table builders (bf16 pairs) =======================
__global__ __launch_bounds__(256)
void make_dft_pair(__bf16* WfH, __bf16* WfL, __bf16* WiH, __bf16* WiL)
{
    const int i = blockIdx.x * 256 + threadIdx.x;
    const double w0 = 2.0 * 3.14159265358979323846 / 256.0;
    {
        const int n = i & 255, r = i >> 8, m = r & 127;
        const double th = (double)((m * n) & 255) * w0;
        const float v = (r < 128) ? (float)cos(th) : (float)-sin(th);
        __bf16 h, l; cvt_hl(v, h, l); WfH[i] = h; WfL[i] = l;
    }
    {
        const int k = i & 255, nn = i >> 8, m = k & 127;
        const double th = (double)((m * nn) & 255) * w0;
        const float sc = (m == 0 ? 1.0f : 2.0f) / 256.0f;
        const float v = (k < 128) ? sc * (float)cos(th) : -sc * (float)sin(th);
        __bf16 h, l; cvt_hl(v, h, l); WiH[i] = h; WiL[i] = l;
    }
}

__global__ __launch_bounds__(256)
void make_P1_pair(const float* __restrict__ pct, const float* __restrict__ wq,
                  __bf16* __restrict__ PH, __bf16* __restrict__ PL)
{
    const long i = (long)blockIdx.x * 256 + threadIdx.x;
    const int y = (int)(i & 127);
    const int l = (int)((i >> 7) & 127);
    const int m = (int)(i >> 14);
    const float v = pct[((long)l * MM + m) * NLAT + y] * wq[y];
    __bf16 h, lo; cvt_hl(v, h, lo); PH[i] = h; PL[i] = lo;
}

__global__ __launch_bounds__(256)
void make_Q_pair(const float* __restrict__ pct, __bf16* __restrict__ QH, __bf16* __restrict__ QL)
{
    __shared__ float t[32][33];
    const int m = blockIdx.z;
    const int y0 = blockIdx.x * 32, l0 = blockIdx.y * 32;
    const int tx = threadIdx.x & 31, tg = threadIdx.x >> 5;
    #pragma unroll
    for (int ll = tg; ll < 32; ll += 8)
        t[ll][tx] = pct[((long)(l0 + ll) * MM + m) * NLAT + (y0 + tx)];
    __syncthreads();
    #pragma unroll
    for (int yy = tg; yy < 32; yy += 8) {
        const long idx = ((long)m * NLAT + (y0 + yy)) * MM + (l0 + tx);
        __bf16 h, l; cvt_hl(t[tx][yy], h, l);
        QH[idx] = h; QL[idx] = l;
    }
}

// ======================= host =======================
extern "C" void kernel_launch(void* const* d_in, const int* in_sizes, int n_in,
                              void* d_out, int out_size, void* d_ws, size_t ws_size,
                              hipStream_t stream)
{
    const float* x       = (const float*)d_in[0];
    const float* pct     = (const float*)d_in[1];
    const float* wq      = (const float*)d_in[2];
    const float* pos     = (const float*)d_in[3];
    const float* enc_w   = (const float*)d_in[4];
    const float* spec_re = (const float*)d_in[5];
    const float* spec_im = (const float*)d_in[6];
    const float* skip_w  = (const float*)d_in[7];
    const float* skip_b  = (const float*)d_in[8];
    const float* mlp_w1  = (const float*)d_in[9];
    const float* mlp_b1  = (const float*)d_in[10];
    const float* mlp_w2  = (const float*)d_in[11];
    const float* mlp_b2  = (const float*)d_in[12];
    const float* dec_w1  = (const float*)d_in[13];
    const float* dec_b1  = (const float*)d_in[14];
    const float* dec_w2  = (const float*)d_in[15];

    char* base = (char*)d_ws;
    size_t off = 0;
    auto alloc = [&](size_t bytes) -> char* {
        char* p = base + off; off += (bytes + 255) & ~(size_t)255; return p;
    };

    // f32 buffers
    float* xT   = (float*)alloc(1179648UL * 4);
    float* hA   = (float*)alloc(8388608UL * 4);
    float* hB   = (float*)alloc(8388608UL * 4);
    float* S1   = (float*)alloc(8388608UL * 4);   // posT pre-loop; u/h2 in-loop; dec2 out
    float* mbuf = (float*)alloc(16777216UL * 4);
    float* D    = (float*)alloc(16777216UL * 4);
    // bf16 buffers
    __bf16* WfH = (__bf16*)alloc(65536UL * 2);
    __bf16* WfL = (__bf16*)alloc(65536UL * 2);
    __bf16* WiH = (__bf16*)alloc(65536UL * 2);
    __bf16* WiL = (__bf16*)alloc(65536UL * 2);
    __bf16* P1H = (__bf16*)alloc(2097152UL * 2);
    __bf16* P1L = (__bf16*)alloc(2097152UL * 2);
    __bf16* QH  = (__bf16*)alloc(2097152UL * 2);
    __bf16* QL  = (__bf16*)alloc(2097152UL * 2);
    __bf16* hcB = (__bf16*)alloc(8388608UL * 2);
    __bf16* SB1 = (__bf16*)alloc(8388608UL * 2);
    __bf16* SB2 = (__bf16*)alloc(8388608UL * 2);
    __bf16* WtR = (__bf16*)alloc(8388608UL * 2);
    __bf16* WtI = (__bf16*)alloc(8388608UL * 2);
    if (off > ws_size) return;

    float* posT = S1;

    // ---- tables ----
    make_dft_pair<<<256, 256, 0, stream>>>(WfH, WfL, WiH, WiL);
    make_P1_pair<<<8192, 256, 0, stream>>>(pct, wq, P1H, P1L);
    make_Q_pair<<<dim3(4, 4, 128), 256, 0, stream>>>(pct, QH, QL);
    transpose2d<<<dim3(1024, 2), 256, 0, stream>>>(x, xT, 36, YN);
    transpose2d<<<dim3(1024, 8), 256, 0, stream>>>(pos, posT, 256, YN);

    // ---- encoder: hA[yn][c] = xT·enc^T + posT ----
    gemm_nt<<<dim3(2, 256), 256, 0, stream>>>(xT, enc_w, hA, YN, EMB, INCH, INCH, INCH, EMB,
                                              nullptr, 0, posT, 1.0f, 0, 0);

    float* hcur = hA;
    float* hnext = hB;

    for (int l = 0; l < NLAYERS; ++l) {
        // t1: h[yn][c] f32 -> hcB[c][yn] bf16
        t_f2b<<<dim3(8, 1024), 256, 0, stream>>>(hcur, hcB, YN, 256);
        // DFT: F[rm][(c,y)] = (WfH+WfL)·hcB^T  -> SB2 bf16
        gemm_sp<<<dim3(256, 2, 1), 256, 0, stream>>>(WfH, WfL, hcB, nullptr,
            256, YN, 256, 256, 256, YN, 0, 0, 0u, 0, nullptr, SB2, 1.0f, 0);
        // legfwd (z=rm): A1[z][c][l] = F_z·(P1H+P1L)_m^T -> SB1
        gemm_sp<<<dim3(1, 2, 256), 256, 0, stream>>>(SB2, nullptr, P1H, P1L,
            256, 128, 128, 128, 128, 128, 32768, 16384, 127u, 32768, nullptr, SB1, 1.0f, 0);
        // t3 per reim: [(m,c)][l] -> [l][(m,c)]
        t_b<<<dim3(4, 1024, 2), 256, 0, stream>>>(SB1, SB2, 32768, 128, RB, RB);
        // spec weights -> [l][(o,i)] bf16
        t_f2b<<<dim3(4, 2048), 256, 0, stream>>>(spec_re + (long)l * 8388608, WtR, 65536, 128);
        t_f2b<<<dim3(4, 2048), 256, 0, stream>>>(spec_im + (long)l * 8388608, WtI, 65536, 128);
        // spec (z=l): Bre = Wr·Ar ; Bim = Wr·Ai  then  Bre -= Wi·Ai ; Bim += Wi·Ar
        gemm_c2<<<dim3(1, 2, 128), 256, 0, stream>>>(WtR, SB2, SB2 + RB, SB1, SB1 + RB,
            256, 256, 256, 128, 65536, 32768, 32768, 1.0f, 0, 1.0f, 0);
        gemm_c2<<<dim3(1, 2, 128), 256, 0, stream>>>(WtI, SB2 + RB, SB2, SB1, SB1 + RB,
            256, 256, 256, 128, 65536, 32768, 32768, -1.0f, 1, 1.0f, 1);
        // rot: Bs[r][l][o][m] -> Bt[r][m][o][l]
        rot3b<<<dim3(4, 4, 512), 256, 0, stream>>>(SB1, SB2, 128, 256, 128, RB, RB);
        // leginv (z=rm, triangular K-start): G[z][c][y] = Bt_z·(QH+QL)_m^T -> SB1
        gemm_sp<<<dim3(1, 2, 256), 256, 0, stream>>>(SB2, nullptr, QH, QL,
            256, 128, 128, 128, 128, 128, 32768, 16384, 127u, 32768, nullptr, SB1, 1.0f, 1);
        // t7: G[rm][(c,y)] -> Gt[(c,y)][rm]
        t_b<<<dim3(1024, 8, 1), 256, 0, stream>>>(SB1, SB2, 256, YN, 0, 0);
        // iDFT (z=y): u[y][w][c] f32 = (WiH+WiL)·Gt_y^T -> S1
        gemm_sp<<<dim3(2, 2, 128), 256, 0, stream>>>(WiH, WiL, SB2, nullptr,
            256, 256, 256, 256, YN, 256, 0, 256, 0xFFFFFFFFu, 65536, S1, nullptr, 1.0f, 0);
        // skip: S1 += h·skip^T + b
        gemm_nt<<<dim3(2, 256), 256, 0, stream>>>(hcur, skip_w + (long)l * 65536, S1,
            YN, EMB, EMB, EMB, EMB, EMB, skip_b + (long)l * EMB, 1, nullptr, 1.0f, 1, 0);
        // mlp1: mbuf = relu(S1·W1^T + b1)
        gemm_nt<<<dim3(4, 256), 256, 0, stream>>>(S1, mlp_w1 + (long)l * 131072, mbuf,
            YN, HID, EMB, EMB, EMB, HID, mlp_b1 + (long)l * HID, 1, nullptr, 1.0f, 0, 1);
        // mlp2: hnext = mbuf·W2^T + b2 + hcur
        gemm_nt<<<dim3(2, 256), 256, 0, stream>>>(mbuf, mlp_w2 + (long)l * 131072, hnext,
            YN, EMB, HID, HID, HID, EMB, mlp_b2 + (long)l * EMB, 1, hcur, 1.0f, 0, 0);
        float* t = hcur; hcur = hnext; hnext = t;
    }

    // ---- decoder ----
    gemm_nt<<<dim3(4, 256), 256, 0, stream>>>(hcur, dec_w1, D, YN, HID, EMB, EMB, 292, HID,
                                              nullptr, 0, nullptr, 1.0f, 0, 0);
    gemm_nt<<<dim3(4, 256), 256, 0, stream>>>(xT, dec_w1 + 256, mbuf, YN, HID, INCH, INCH, 292, HID,
                                              dec_b1, 1, D, 1.0f, 0, 1);
    gemm_nt<<<dim3(1, 256), 256, 0, stream>>>(mbuf, dec_w2, S1, YN, OUTCH, HID, HID, HID, OUTCH,
                                              nullptr, 0, nullptr, 1.0f, 0, 0);
    transpose2d<<<dim3(1, 1024), 256, 0, stream>>>(S1, (float*)d_out, YN, OUTCH);

    (void)in_sizes; (void)n_in; (void)out_size;
}